// Round 1
// baseline (46.892 us; speedup 1.0000x reference)
//
#include <hip/hip_runtime.h>

// Output = encode_output.sum(axis=1): [B, S, EOUT] -> [B, 1, EOUT]
// (softmax over a size-1 axis == 1.0, so the MLP branch is dead code)

constexpr int B_    = 32;
constexpr int S_    = 2048;
constexpr int EOUT  = 1024;           // 2 * ENC_H
constexpr int E4PB  = 8;              // float4 per block chunk (32 floats)
constexpr int ECH   = EOUT / (E4PB * 4); // 32 e-chunks per batch
constexpr int SSPL  = 32;             // s-split ways per block

__device__ __forceinline__ void f4acc(float4& a, const float4 b) {
    a.x += b.x; a.y += b.y; a.z += b.z; a.w += b.w;
}

__global__ __launch_bounds__(256) void rowsum_kernel(const float* __restrict__ enc,
                                                     float* __restrict__ out) {
    const int bx  = blockIdx.x;
    const int b   = bx >> 5;          // / ECH
    const int ec  = bx & (ECH - 1);
    const int tid = threadIdx.x;
    const int e4  = tid & (E4PB - 1); // which float4 within chunk
    const int ss  = tid >> 3;         // 0..31  s-split lane

    const float4* base =
        reinterpret_cast<const float4*>(enc + (size_t)b * S_ * EOUT + ec * (E4PB * 4)) + e4;
    // row stride in float4 units:
    constexpr int RS = EOUT / 4;      // 256

    float4 a0 = make_float4(0.f, 0.f, 0.f, 0.f);
    float4 a1 = make_float4(0.f, 0.f, 0.f, 0.f);
    float4 a2 = make_float4(0.f, 0.f, 0.f, 0.f);
    float4 a3 = make_float4(0.f, 0.f, 0.f, 0.f);

    // s = ss, ss+32, ... : 64 loads/thread, 4 independent accumulators
    #pragma unroll
    for (int s = 0; s < S_; s += 4 * SSPL) {
        f4acc(a0, base[(size_t)(s + ss) * RS]);
        f4acc(a1, base[(size_t)(s + ss + SSPL) * RS]);
        f4acc(a2, base[(size_t)(s + ss + 2 * SSPL) * RS]);
        f4acc(a3, base[(size_t)(s + ss + 3 * SSPL) * RS]);
    }
    f4acc(a0, a1); f4acc(a2, a3); f4acc(a0, a2);

    __shared__ float4 lds[256];
    lds[tid] = a0;
    __syncthreads();

    #pragma unroll
    for (int off = 128; off >= E4PB; off >>= 1) {
        if (tid < off) {
            float4 t = lds[tid + off];
            f4acc(lds[tid], t);
        }
        __syncthreads();
    }

    if (tid < E4PB) {
        float4 r = lds[tid];
        reinterpret_cast<float4*>(out + (size_t)b * EOUT + ec * (E4PB * 4))[tid] = r;
    }
}

extern "C" void kernel_launch(void* const* d_in, const int* in_sizes, int n_in,
                              void* d_out, int out_size, void* d_ws, size_t ws_size,
                              hipStream_t stream) {
    const float* enc = (const float*)d_in[0];
    float* out = (float*)d_out;
    rowsum_kernel<<<dim3(B_ * ECH), dim3(256), 0, stream>>>(enc, out);
}